// Round 10
// baseline (152.749 us; speedup 1.0000x reference)
//
#include <hip/hip_runtime.h>
#include <hip/hip_bf16.h>

#define N_NODES 50000
#define N_EDGES 800000
#define DIM     128
#define N_BKT    782                          // bucket = dst >> 6 (64 nodes/bucket)
#define CHUNK_E  4096                         // edges per scatter chunk
#define EDGE_CHUNKS 196                       // 195*4096 + 1280
#define BCAP     1536                         // bucket region cap (mean 1024, 16 sigma)
#define EBUF_CAP 1408                         // LDS sorted-edge cap (mean 1024, 12 sigma)
#define CONV_B0  196
#define CONV_NB  112
#define PACK1_B0 308
#define PACK2_B0 312
#define D1_BLOCKS 316
#define AGS      68                           // agg LDS row stride (dwords)
#define BPAD     32                           // bcnt stride: 1 counter per 128B line

typedef short short8 __attribute__((ext_vector_type(8)));
typedef float floatx4 __attribute__((ext_vector_type(4)));

// fp32 -> bf16 (RNE) bit pattern
__device__ inline unsigned short f2bf(float f) {
    __hip_bfloat16 h = __float2bfloat16(f);
    return *reinterpret_cast<unsigned short*>(&h);
}

__device__ inline uint4 pack8(const float a[8]) {
    uint4 o;
    o.x = (unsigned)f2bf(a[0]) | ((unsigned)f2bf(a[1]) << 16);
    o.y = (unsigned)f2bf(a[2]) | ((unsigned)f2bf(a[3]) << 16);
    o.z = (unsigned)f2bf(a[4]) | ((unsigned)f2bf(a[5]) << 16);
    o.w = (unsigned)f2bf(a[6]) | ((unsigned)f2bf(a[7]) << 16);
    return o;
}

// ---------------------------------------------------------------------------
// Dispatch 1 (316 blocks x 512 threads):
//  [0,196):   LDS-sorted bucket scatter. 512 thr = 8 waves per block -> 2x
//             the scattered-store streams per CU (the suspected fused1 cap:
//             per-CU line-RMW throughput on the bucketed writeout).
//  [196,308): x f32 -> bf16 convert (xb)
//  [308,312): pack W1 fragments -> pw1
//  [312,316): pack W2 fragments -> pw2
// ---------------------------------------------------------------------------
__global__ __launch_bounds__(512) void fused1(
    const float* __restrict__ x, const float* __restrict__ W1,
    const float* __restrict__ W2,
    const int* __restrict__ src, const int* __restrict__ dst,
    const float* __restrict__ vals,
    unsigned int* __restrict__ xb, int* __restrict__ bcnt,
    int2* __restrict__ bucketed,
    uint4* __restrict__ p1, uint4* __restrict__ p2)
{
    __shared__ __align__(16) int2 ebuf[CHUNK_E];   // 32 KB sorted chunk
    __shared__ int hist[1024];
    __shared__ int lstart[1024];
    __shared__ int gbase[1024];
    __shared__ int lcur[1024];
    __shared__ int tsum[256];
    const int t = threadIdx.x;

    if (blockIdx.x < EDGE_CHUNKS) {
        // ---------------- LDS-sorted bucket scatter ----------------
        const int chunk = blockIdx.x;
        const int base  = chunk * CHUNK_E;
        const int nav   = min(CHUNK_E, N_EDGES - base);  // 4096 or 1280; %4==0
        for (int i = t; i < 1024; i += 512) hist[i] = 0;
        __syncthreads();

        // phase 1: bucket histogram (512 thr x 2 iters covers 1024 int4)
        const int4* d4 = reinterpret_cast<const int4*>(dst + base);
        #pragma unroll
        for (int i = 0; i < 2; ++i) {
            const int j = t + i * 512;
            if (j * 4 < nav) {
                const int4 d = d4[j];
                atomicAdd(&hist[d.x >> 6], 1);
                atomicAdd(&hist[d.y >> 6], 1);
                atomicAdd(&hist[d.z >> 6], 1);
                atomicAdd(&hist[d.w >> 6], 1);
            }
        }
        __syncthreads();

        // phase 2: scan — threads <256 own 4 buckets + Hillis-Steele
        int h0 = 0, h1 = 0, h2 = 0, h3 = 0, s = 0;
        if (t < 256) {
            h0 = hist[4*t]; h1 = hist[4*t+1]; h2 = hist[4*t+2]; h3 = hist[4*t+3];
            s = h0 + h1 + h2 + h3;
            tsum[t] = s;
        }
        __syncthreads();
        for (int off = 1; off < 256; off <<= 1) {
            int u = 0;
            if (t < 256 && t >= off) u = tsum[t - off];
            __syncthreads();
            if (t < 256 && t >= off) tsum[t] += u;
            __syncthreads();
        }
        if (t < 256) {
            const int ex = tsum[t] - s;                 // exclusive thread base
            lstart[4*t]   = ex;
            lstart[4*t+1] = ex + h0;
            lstart[4*t+2] = ex + h0 + h1;
            lstart[4*t+3] = ex + h0 + h1 + h2;
            lcur[4*t]   = ex;
            lcur[4*t+1] = ex + h0;
            lcur[4*t+2] = ex + h0 + h1;
            lcur[4*t+3] = ex + h0 + h1 + h2;
        }
        // global range reservation per bucket (line-padded counters)
        for (int b = t; b < N_BKT; b += 512)
            gbase[b] = b * BCAP + atomicAdd(&bcnt[b * BPAD], hist[b]);
        __syncthreads();

        // phase 3: place payloads sorted into ebuf (bucket id in bits 22-31)
        const int4*   s4 = reinterpret_cast<const int4*>(src + base);
        const float4* v4 = reinterpret_cast<const float4*>(vals + base);
        #pragma unroll
        for (int i = 0; i < 2; ++i) {
            const int j = t + i * 512;
            if (j * 4 < nav) {
                const int4   sw = s4[j];
                const int4   dw = d4[j];
                const float4 vw = v4[j];
                int b, p;
                b = dw.x >> 6; p = atomicAdd(&lcur[b], 1);
                ebuf[p] = make_int2((sw.x & 0xFFFF) | ((dw.x & 63) << 16) | (b << 22), __float_as_int(vw.x));
                b = dw.y >> 6; p = atomicAdd(&lcur[b], 1);
                ebuf[p] = make_int2((sw.y & 0xFFFF) | ((dw.y & 63) << 16) | (b << 22), __float_as_int(vw.y));
                b = dw.z >> 6; p = atomicAdd(&lcur[b], 1);
                ebuf[p] = make_int2((sw.z & 0xFFFF) | ((dw.z & 63) << 16) | (b << 22), __float_as_int(vw.z));
                b = dw.w >> 6; p = atomicAdd(&lcur[b], 1);
                ebuf[p] = make_int2((sw.w & 0xFFFF) | ((dw.w & 63) << 16) | (b << 22), __float_as_int(vw.w));
            }
        }
        __syncthreads();

        // phase 4: run-contiguous writeout, 8 waves of store streams
        for (int i = t; i < nav; i += 512) {
            const int2 e = ebuf[i];
            const int  b = ((unsigned)e.x) >> 22;
            bucketed[gbase[b] + (i - lstart[b])] = make_int2(e.x & 0x3FFFFF, e.y);
        }
    } else if (blockIdx.x < PACK1_B0) {
        // ---------------- x -> bf16 convert (streaming) ----------------
        const int cb = blockIdx.x - CONV_B0;
        const float4* x4 = reinterpret_cast<const float4*>(x);
        uint2* xb2 = reinterpret_cast<uint2*>(xb);
        for (int i = cb * 512 + t; i < N_NODES * DIM / 4; i += CONV_NB * 512) {
            const float4 f = x4[i];
            uint2 o;
            o.x = (unsigned)f2bf(f.x) | ((unsigned)f2bf(f.y) << 16);
            o.y = (unsigned)f2bf(f.z) | ((unsigned)f2bf(f.w) << 16);
            xb2[i] = o;
        }
    } else if (blockIdx.x < PACK2_B0) {
        // ---------------- pack W1: B[k][n] = W1[k][n] ----------------
        const int sI   = (blockIdx.x - PACK1_B0) * 512 + t;   // 0..2047
        const int lane = sI & 63;
        const int nt   = (sI >> 6) & 7;
        const int ks   = sI >> 9;
        const int m    = lane & 15;
        const int q    = lane >> 4;
        unsigned short e[8];
        #pragma unroll
        for (int j = 0; j < 8; ++j)
            e[j] = f2bf(W1[(ks * 32 + q * 8 + j) * DIM + nt * 16 + m]);
        uint4 o;
        o.x = (unsigned)e[0] | ((unsigned)e[1] << 16);
        o.y = (unsigned)e[2] | ((unsigned)e[3] << 16);
        o.z = (unsigned)e[4] | ((unsigned)e[5] << 16);
        o.w = (unsigned)e[6] | ((unsigned)e[7] << 16);
        p1[sI] = o;
    } else {
        // ---------------- pack W2: B[k][n] = W2[n][k] ----------------
        const int sI   = (blockIdx.x - PACK2_B0) * 512 + t;
        const int lane = sI & 63;
        const int nt   = (sI >> 6) & 7;
        const int ks   = sI >> 9;
        const int m    = lane & 15;
        const int q    = lane >> 4;
        const float4 f0 = *reinterpret_cast<const float4*>(&W2[(nt * 16 + m) * DIM + ks * 32 + q * 8]);
        const float4 f1 = *reinterpret_cast<const float4*>(&W2[(nt * 16 + m) * DIM + ks * 32 + q * 8 + 4]);
        unsigned short e[8];
        e[0] = f2bf(f0.x); e[1] = f2bf(f0.y); e[2] = f2bf(f0.z); e[3] = f2bf(f0.w);
        e[4] = f2bf(f1.x); e[5] = f2bf(f1.y); e[6] = f2bf(f1.z); e[7] = f2bf(f1.w);
        uint4 o;
        o.x = (unsigned)e[0] | ((unsigned)e[1] << 16);
        o.y = (unsigned)e[2] | ((unsigned)e[3] << 16);
        o.z = (unsigned)e[4] | ((unsigned)e[5] << 16);
        o.w = (unsigned)e[6] | ((unsigned)e[7] << 16);
        p2[sI] = o;
    }
}

// ---------------------------------------------------------------------------
// Dispatch 2: one block (512 thr, 8 waves) per 64-node bucket.
// (byte-identical to round 9 — at the compulsory-L3-traffic floor)
// ---------------------------------------------------------------------------
__global__ __launch_bounds__(512) void agg_gemms(
    const unsigned int* __restrict__ xb, const int2* __restrict__ bucketed,
    const int* __restrict__ bcnt,
    const short8* __restrict__ Bp1, const short8* __restrict__ Bp2,
    const float* __restrict__ bias1, const float* __restrict__ bias2,
    float* __restrict__ out)
{
    __shared__ int2 ebuf[EBUF_CAP];            // 11264 B
    __shared__ unsigned int agg[64 * AGS];     // 17408 B
    __shared__ float sv[64];
    __shared__ int cnt[64];
    __shared__ int coff[64];
    __shared__ int cur[64];

    const int b = blockIdx.x;
    const int t = threadIdx.x;
    int nE = bcnt[b * BPAD];
    if (nE > EBUF_CAP) nE = EBUF_CAP;          // 12-sigma guard, never taken
    const int base = b * BCAP;

    // ---- phase A: counting sort by dst&63 into ebuf ----
    if (t < 64) cnt[t] = 0;
    __syncthreads();
    for (int i = t; i < nE; i += 512)
        atomicAdd(&cnt[(bucketed[base + i].x >> 16) & 63], 1);
    __syncthreads();
    if (t < 64) coff[t] = cnt[t];
    __syncthreads();
    for (int off = 1; off < 64; off <<= 1) {
        int u = 0;
        if (t < 64 && t >= off) u = coff[t - off];
        __syncthreads();
        if (t < 64 && t >= off) coff[t] += u;
        __syncthreads();
    }
    if (t < 64) cur[t] = coff[t] - cnt[t];     // exclusive prefix
    __syncthreads();
    for (int i = t; i < nE; i += 512) {
        const int2 e = bucketed[base + i];
        const int  n = (e.x >> 16) & 63;
        const int  p = atomicAdd(&cur[n], 1);
        ebuf[p] = e;
    }
    __syncthreads();

    // ---- phase B: wave w -> nodes w*8..+8; gather xb rows + sumval ----
    const int w    = t >> 6;
    const int lane = t & 63;
    const int g    = lane >> 4;                // edge sub-slot 0..3
    const int dl   = lane & 15;                // dim block: dims 8*dl..+8

    for (int nl = w * 8; nl < w * 8 + 8; ++nl) {
        const int end = cur[nl];               // = excl + cnt after scatter
        const int c   = cnt[nl];
        const int beg = end - c;
        float acc[8];
        #pragma unroll
        for (int k = 0; k < 8; ++k) acc[k] = 0.f;
        float sval = 0.f;

        const int nI = (c + 3) >> 2;           // instructions (4 edges each)
        auto step = [&](int it) {
            const int  idx = beg + it * 4 + g;
            const bool vld = idx < end;
            const int2 e   = ebuf[vld ? idx : beg];
            const float val = vld ? __int_as_float(e.y) : 0.f;
            const uint4 u = *reinterpret_cast<const uint4*>(
                &xb[(size_t)(e.x & 0xFFFF) * 64 + dl * 4]);
            sval += val;
            acc[0] += __uint_as_float(u.x << 16)          * val;
            acc[1] += __uint_as_float(u.x & 0xffff0000u)  * val;
            acc[2] += __uint_as_float(u.y << 16)          * val;
            acc[3] += __uint_as_float(u.y & 0xffff0000u)  * val;
            acc[4] += __uint_as_float(u.z << 16)          * val;
            acc[5] += __uint_as_float(u.z & 0xffff0000u)  * val;
            acc[6] += __uint_as_float(u.w << 16)          * val;
            acc[7] += __uint_as_float(u.w & 0xffff0000u)  * val;
        };
        int it = 0;
        for (; it + 3 < nI; it += 4) { step(it); step(it+1); step(it+2); step(it+3); }
        for (; it < nI; ++it) step(it);

        // combine partial sums across the 4 lane-quarters (g dimension)
        #pragma unroll
        for (int k = 0; k < 8; ++k) {
            acc[k] += __shfl_xor(acc[k], 16);
            acc[k] += __shfl_xor(acc[k], 32);
        }
        sval += __shfl_xor(sval, 16);
        sval += __shfl_xor(sval, 32);
        if (lane == 0) sv[nl] = sval;
        if (lane < 16) {                       // lanes 0..15 write the row (NO relu)
            *reinterpret_cast<uint4*>(&agg[nl * AGS + dl * 4]) = pack8(acc);
        }
    }
    __syncthreads();

    // ---- phase C1 (waves 0-3): GEMM1 + sumval*b1, relu, bf16 -> agg ----
    const bool act = (w < 4) && (b * 64 + w * 16 < N_NODES);  // bucket 781 tail
    const int m = lane & 15;
    const int q = lane >> 4;
    unsigned short* aggs = reinterpret_cast<unsigned short*>(agg);

    if (act) {
        short8 a[4];
        #pragma unroll
        for (int ks = 0; ks < 4; ++ks) {
            const uint4 t4 = *reinterpret_cast<const uint4*>(&agg[(w * 16 + m) * AGS + ks * 16 + q * 4]);
            a[ks] = *reinterpret_cast<const short8*>(&t4);
        }
        floatx4 acc[8];
        #pragma unroll
        for (int nt = 0; nt < 8; ++nt) { acc[nt][0]=0.f; acc[nt][1]=0.f; acc[nt][2]=0.f; acc[nt][3]=0.f; }
        #pragma unroll
        for (int ks = 0; ks < 4; ++ks) {
            #pragma unroll
            for (int nt = 0; nt < 8; ++nt) {
                const short8 bf = Bp1[(ks * 8 + nt) * 64 + lane];
                acc[nt] = __builtin_amdgcn_mfma_f32_16x16x32_bf16(a[ks], bf, acc[nt], 0, 0, 0);
            }
        }
        float sv4[4];
        #pragma unroll
        for (int i = 0; i < 4; ++i) sv4[i] = sv[w * 16 + q * 4 + i];
        #pragma unroll
        for (int nt = 0; nt < 8; ++nt) {
            const float bb = bias1[nt * 16 + m];
            #pragma unroll
            for (int i = 0; i < 4; ++i) {
                const float v = fmaxf(acc[nt][i] + sv4[i] * bb, 0.f);
                aggs[(w * 16 + q * 4 + i) * (AGS * 2) + nt * 16 + m] = f2bf(v);
            }
        }
    }
    __syncthreads();

    // ---- phase C2 (waves 0-3): GEMM2 + bias + row L2-norm ----
    if (!act) return;
    const int row0 = b * 64 + w * 16;

    short8 a[4];
    #pragma unroll
    for (int ks = 0; ks < 4; ++ks) {
        const uint4 t4 = *reinterpret_cast<const uint4*>(&aggs[(w * 16 + m) * (AGS * 2) + ks * 32 + q * 8]);
        a[ks] = *reinterpret_cast<const short8*>(&t4);
    }

    floatx4 acc[8];
    #pragma unroll
    for (int nt = 0; nt < 8; ++nt) { acc[nt][0]=0.f; acc[nt][1]=0.f; acc[nt][2]=0.f; acc[nt][3]=0.f; }

    #pragma unroll
    for (int ks = 0; ks < 4; ++ks) {
        #pragma unroll
        for (int nt = 0; nt < 8; ++nt) {
            const short8 bf = Bp2[(ks * 8 + nt) * 64 + lane];
            acc[nt] = __builtin_amdgcn_mfma_f32_16x16x32_bf16(a[ks], bf, acc[nt], 0, 0, 0);
        }
    }

    #pragma unroll
    for (int nt = 0; nt < 8; ++nt) {
        const float bb = bias2[nt * 16 + m];
        #pragma unroll
        for (int i = 0; i < 4; ++i) acc[nt][i] += bb;
    }

    float sq[4] = {0.f, 0.f, 0.f, 0.f};
    #pragma unroll
    for (int nt = 0; nt < 8; ++nt)
        #pragma unroll
        for (int i = 0; i < 4; ++i) sq[i] += acc[nt][i] * acc[nt][i];
    #pragma unroll
    for (int i = 0; i < 4; ++i) {
        #pragma unroll
        for (int mask = 1; mask < 16; mask <<= 1)
            sq[i] += __shfl_xor(sq[i], mask);
        sq[i] = 1.0f / sqrtf(sq[i]);
    }

    #pragma unroll
    for (int nt = 0; nt < 8; ++nt) {
        #pragma unroll
        for (int i = 0; i < 4; ++i) {
            const int r = row0 + q * 4 + i;
            out[(size_t)r * DIM + nt * 16 + m] = acc[nt][i] * sq[i];
        }
    }
}

// ---------------------------------------------------------------------------
extern "C" void kernel_launch(void* const* d_in, const int* in_sizes, int n_in,
                              void* d_out, int out_size, void* d_ws, size_t ws_size,
                              hipStream_t stream) {
    const float* x    = (const float*)d_in[0];
    const float* vals = (const float*)d_in[1];
    const float* W_gc = (const float*)d_in[2];
    const float* b_gc = (const float*)d_in[3];
    const float* W2   = (const float*)d_in[4];
    const float* b2   = (const float*)d_in[5];
    const int*   src  = (const int*)d_in[6];
    const int*   dst  = (const int*)d_in[7];

    float* out = (float*)d_out;

    // ws layout (16B-aligned)
    const size_t XB_B  = (size_t)N_NODES * DIM * 2;      // 12,800,000 (bf16 x)
    const size_t BUK_B = (size_t)N_BKT * BCAP * 8;       // 9,609,216
    const size_t BC_B  = (size_t)800 * BPAD * 4;         // 102,400 (line-padded)
    char* wsb = (char*)d_ws;
    unsigned int* xb = (unsigned int*)wsb;
    int2*  bucketed = (int2*)(wsb + XB_B);
    int*   bcnt     = (int*)(wsb + XB_B + BUK_B);
    uint4* pw1      = (uint4*)(wsb + XB_B + BUK_B + BC_B);
    uint4* pw2      = (uint4*)(wsb + XB_B + BUK_B + BC_B + 32768);

    // 0. zero line-padded bucket counters (graph-capturable async memset)
    hipMemsetAsync(bcnt, 0, BC_B, stream);

    // 1. LDS-sorted scatter (8-wave store streams) || convert || packs
    fused1<<<D1_BLOCKS, 512, 0, stream>>>(
        x, W_gc, W2, src, dst, vals, xb, bcnt, bucketed, pw1, pw2);

    // 2. per-bucket: sort -> gather(xb)+sumval -> GEMM1+relu -> GEMM2+norm
    agg_gemms<<<N_BKT, 512, 0, stream>>>(
        xb, bucketed, bcnt, (const short8*)pw1, (const short8*)pw2,
        b_gc, b2, out);
}